// Round 3
// baseline (2020.926 us; speedup 1.0000x reference)
//
#include <hip/hip_runtime.h>
#include <hip/hip_bf16.h>
#include <stdint.h>

#define Bh 64
#define Nn 4096
#define Dd 256
#define Kk 15
#define Hh 512
#define BN (Bh*Nn)
#define EPSN 1e-8f
#define LN_EPS 1e-5f

typedef __attribute__((ext_vector_type(8))) short short8;
typedef __attribute__((ext_vector_type(4))) float f32x4;

__device__ __forceinline__ float bflo(unsigned u){ return __uint_as_float(u << 16); }
__device__ __forceinline__ float bfhi(unsigned u){ return __uint_as_float(u & 0xffff0000u); }
__device__ __forceinline__ unsigned short f2bf(float f){
    unsigned b = __float_as_uint(f);
    b += 0x7fffu + ((b >> 16) & 1u);   // RNE
    return (unsigned short)(b >> 16);
}
__device__ __forceinline__ float sigm_(float x){ return 1.f/(1.f+__expf(-x)); }
__device__ __forceinline__ float tanh_(float x){ return 1.f - 2.f/(__expf(2.f*x)+1.f); }

__device__ __forceinline__ void async16(const void* g, void* l){
    __builtin_amdgcn_global_load_lds((const __attribute__((address_space(1))) void*)g,
                                     (__attribute__((address_space(3))) void*)l, 16, 0, 0);
}

// ---------------- workspace layout (bytes) ----------------
// PART aliases xbf (xbf dead after k_proj)
#define OFF_X    ((size_t)0)                         // xbf 134217728 ; PART (16.7MB) aliases
#define OFF_K    (OFF_X  + (size_t)BN*256*2)         // k bf16 rows of 256
#define OFF_VT   (OFF_K  + (size_t)BN*256*2)         // vT bf16 [b][256][4096]
#define OFF_WC   (OFF_VT + (size_t)BN*256*2)         // Wc bf16 512*256
#define OFF_QBF  (OFF_WC + (size_t)512*256*2)        // q bf16 [b][16][256]
#define OFF_S    (OFF_QBF+ (size_t)64*16*256*2)
#define OFF_G    (OFF_S  + (size_t)983040)
#define OFF_SN   (OFF_G  + (size_t)983040)
#define OFF_UPD  (OFF_SN + (size_t)983040)
#define OFF_ASUM (OFF_UPD+ (size_t)983040)           // 4096
#define OFF_GT   (OFF_ASUM+(size_t)4096)
#define OFF_H1   (OFF_GT + (size_t)960*1536*4)

// ---------------- prep ----------------
__global__ __launch_bounds__(256) void k_prep_wc(const float* __restrict__ Wk, const float* __restrict__ Wv,
                                                 unsigned short* __restrict__ Wc){
    int i = blockIdx.x*256 + threadIdx.x;
    int n = i >> 8, e = i & 255;
    float w = (n < 256) ? Wk[n*256+e] : Wv[(n-256)*256+e];
    Wc[i] = f2bf(w);
}

__global__ __launch_bounds__(256) void k_slots_init(const float* __restrict__ mu, const float* __restrict__ lsig,
                                                    const float* __restrict__ noise, float* __restrict__ S){
    int i = blockIdx.x*256 + threadIdx.x;
    int j = i % (Kk*Dd);
    S[i] = mu[j] + __expf(lsig[j]) * noise[i];
}

__global__ __launch_bounds__(256) void k_ln_in(const float* __restrict__ x, const float* __restrict__ g,
                                               const float* __restrict__ b, unsigned short* __restrict__ out){
    int wave = threadIdx.x >> 6, lane = threadIdx.x & 63;
    size_t row = (size_t)blockIdx.x*4 + wave;
    const float4* xr = (const float4*)(x + row*Dd);
    float4 v = xr[lane];
    float s  = v.x+v.y+v.z+v.w;
    float ss = v.x*v.x+v.y*v.y+v.z*v.z+v.w*v.w;
    for (int m=1;m<64;m<<=1){ s += __shfl_xor(s,m); ss += __shfl_xor(ss,m); }
    float mean = s*(1.f/Dd);
    float rstd = rsqrtf(ss*(1.f/Dd) - mean*mean + LN_EPS);
    float4 gv = ((const float4*)g)[lane], bv = ((const float4*)b)[lane];
    ushort4 o;
    o.x = f2bf((v.x-mean)*rstd*gv.x + bv.x);
    o.y = f2bf((v.y-mean)*rstd*gv.y + bv.y);
    o.z = f2bf((v.z-mean)*rstd*gv.z + bv.z);
    o.w = f2bf((v.w-mean)*rstd*gv.w + bv.w);
    *(ushort4*)(out + row*Dd + lane*4) = o;
}

__global__ __launch_bounds__(256) void k_ln_rows(const float* __restrict__ x, const float* __restrict__ g,
                                                 const float* __restrict__ b, float* __restrict__ out){
    int wave = threadIdx.x >> 6, lane = threadIdx.x & 63;
    size_t row = (size_t)blockIdx.x*4 + wave;
    const float4* xr = (const float4*)(x + row*Dd);
    float4 v = xr[lane];
    float s  = v.x+v.y+v.z+v.w;
    float ss = v.x*v.x+v.y*v.y+v.z*v.z+v.w*v.w;
    for (int m=1;m<64;m<<=1){ s += __shfl_xor(s,m); ss += __shfl_xor(ss,m); }
    float mean = s*(1.f/Dd);
    float rstd = rsqrtf(ss*(1.f/Dd) - mean*mean + LN_EPS);
    float4 gv = ((const float4*)g)[lane], bv = ((const float4*)b)[lane];
    float4 o;
    o.x = (v.x-mean)*rstd*gv.x + bv.x;
    o.y = (v.y-mean)*rstd*gv.y + bv.y;
    o.z = (v.z-mean)*rstd*gv.z + bv.z;
    o.w = (v.w-mean)*rstd*gv.w + bv.w;
    *(float4*)(out + row*Dd + lane*4) = o;
}

// ---------------- MFMA projection: [k | vT] = LN(x)_bf16 @ [Wk;Wv]^T ----------------
// A-panel-resident + hand-unrolled depth-2 register pipeline for B (3 named
// quarter-unit buffers, all indices compile-time -> no scratch, no dynamic idx).
__global__ __launch_bounds__(512, 4) void k_proj(const unsigned short* __restrict__ A,
                                                 const unsigned short* __restrict__ Bw,
                                                 unsigned short* __restrict__ kb,
                                                 unsigned short* __restrict__ vT){
    __shared__ short As[128*256];   // 64 KB: rows of 32 chunks(16B), chunk' = chunk ^ (row&7)
    int tid = threadIdx.x;
    int w = tid >> 6, lane = tid & 63;
    int m0 = blockIdx.x*128;
    int wr = w >> 2, wc = w & 3;           // 8 waves: 2 (rows) x 4 (cols)
    int lr = lane & 15, lg = lane >> 4;

    // stage A panel: 8 rounds x 512 threads x 16B, source pre-swizzled (both-sides rule)
#pragma unroll
    for (int j=0;j<8;j++){
        int idx = j*512 + tid;            // 0..4095
        int row = idx >> 5, chp = idx & 31;
        int ch  = chp ^ (row & 7);        // involution
        async16((const char*)A + ((size_t)(m0+row)*256 + ch*8)*2, (char*)As + (size_t)idx*16);
    }

    const unsigned short* bwl = Bw + (size_t)(wc*32 + lr)*256 + lg*8;

    // unit t (0..15): nt=t>>2, hf=(t>>1)&1, u=t&1 ; covers ks = hf*4+u*2+{0,1}, ni={0,1}
    short8 A_0,A_1,A_2,A_3, B_0,B_1,B_2,B_3, C_0,C_1,C_2,C_3;
    f32x4 acc00,acc01,acc10,acc11,acc20,acc21,acc30,acc31;

#define ISSUE(P, t_) { \
    const unsigned short* bp_ = bwl + ((t_)>>2)*32768 + (((t_)>>1)&1)*128 + ((t_)&1)*64; \
    P##0 = *(const short8*)(bp_); \
    P##1 = *(const short8*)(bp_ + 32); \
    P##2 = *(const short8*)(bp_ + 4096); \
    P##3 = *(const short8*)(bp_ + 4096 + 32); }
#define LDA(mi_, ks_) (*(const short8*)((const char*)As + (wr*64 + (mi_)*16 + lr)*512 + ((((ks_)*4+lg))^swz)*16))
#define MF(a_,b_,c_) __builtin_amdgcn_mfma_f32_16x16x32_bf16(a_,b_,c_,0,0,0)
#define COMPQ(F0, F1, ks_) { \
    short8 af0=LDA(0,ks_), af1=LDA(1,ks_), af2=LDA(2,ks_), af3=LDA(3,ks_); \
    acc00=MF(af0,F0,acc00); acc01=MF(af0,F1,acc01); \
    acc10=MF(af1,F0,acc10); acc11=MF(af1,F1,acc11); \
    acc20=MF(af2,F0,acc20); acc21=MF(af2,F1,acc21); \
    acc30=MF(af3,F0,acc30); acc31=MF(af3,F1,acc31); }
#define COMPU(P, t_) { COMPQ(P##0, P##2, ((((t_)>>1)&1)*4 + ((t_)&1)*2 + 0)); \
                       COMPQ(P##1, P##3, ((((t_)>>1)&1)*4 + ((t_)&1)*2 + 1)); }
#define ZERO { acc00=acc01=acc10=acc11=acc20=acc21=acc30=acc31=(f32x4){0.f,0.f,0.f,0.f}; }
#define STK(nt_, mi_, ni_, A_) { \
    int gn_ = (nt_)*128 + wc*32 + (ni_)*16 + cn; \
    _Pragma("unroll") for (int r=0;r<4;r++){ \
        size_t gm_ = (size_t)m0 + wr*64 + (mi_)*16 + cr + r; \
        kb[gm_*256 + gn_] = f2bf(A_[r]); } }
#define STV(nt_, mi_, ni_, A_) { \
    int nl_ = nl0 + wr*64 + (mi_)*16 + cr; \
    int d_  = ((nt_)-2)*128 + wc*32 + (ni_)*16 + cn; \
    ushort4 o_; o_.x=f2bf(A_[0]); o_.y=f2bf(A_[1]); o_.z=f2bf(A_[2]); o_.w=f2bf(A_[3]); \
    *(ushort4*)(vT + ((size_t)bb*256 + d_)*4096 + nl_) = o_; }
#define EPI_K(nt_) { STK(nt_,0,0,acc00) STK(nt_,0,1,acc01) STK(nt_,1,0,acc10) STK(nt_,1,1,acc11) \
                     STK(nt_,2,0,acc20) STK(nt_,2,1,acc21) STK(nt_,3,0,acc30) STK(nt_,3,1,acc31) }
#define EPI_V(nt_) { STV(nt_,0,0,acc00) STV(nt_,0,1,acc01) STV(nt_,1,0,acc10) STV(nt_,1,1,acc11) \
                     STV(nt_,2,0,acc20) STV(nt_,2,1,acc21) STV(nt_,3,0,acc30) STV(nt_,3,1,acc31) }

    ISSUE(A_,0) ISSUE(B_,1) ISSUE(C_,2)
    __syncthreads();                       // single barrier; drains staging (and first units)

    int bb  = m0 >> 12;                    // batch (128 | 4096 so constant per block)
    int nl0 = m0 & 4095;
    int cn = lr, cr = lg*4;
    int swz = lr & 7;

    ZERO
    COMPU(A_,0)  ISSUE(A_,3)
    COMPU(B_,1)  ISSUE(B_,4)
    COMPU(C_,2)  ISSUE(C_,5)
    COMPU(A_,3)  ISSUE(A_,6)
    EPI_K(0) ZERO
    COMPU(B_,4)  ISSUE(B_,7)
    COMPU(C_,5)  ISSUE(C_,8)
    COMPU(A_,6)  ISSUE(A_,9)
    COMPU(B_,7)  ISSUE(B_,10)
    EPI_K(1) ZERO
    COMPU(C_,8)  ISSUE(C_,11)
    COMPU(A_,9)  ISSUE(A_,12)
    COMPU(B_,10) ISSUE(B_,13)
    COMPU(C_,11) ISSUE(C_,14)
    EPI_V(2) ZERO
    COMPU(A_,12) ISSUE(A_,15)
    COMPU(B_,13)
    COMPU(C_,14)
    COMPU(A_,15)
    EPI_V(3)

#undef ISSUE
#undef LDA
#undef MF
#undef COMPQ
#undef COMPU
#undef ZERO
#undef STK
#undef STV
#undef EPI_K
#undef EPI_V
}

// ---------------- q = LN(slots) @ Wq^T -> bf16 [b][16][256] ----------------
__global__ __launch_bounds__(256) void k_q(const float* __restrict__ sn, const float* __restrict__ Wq,
                                           unsigned short* __restrict__ qbf){
    int b = blockIdx.x, c = threadIdx.x;
    const float4* wr = (const float4*)(Wq + (size_t)c*256);
    const float4* s4 = (const float4*)(sn + (size_t)b*Kk*Dd);
    float acc[15];
#pragma unroll
    for (int r=0;r<15;r++) acc[r] = 0.f;
    for (int e=0;e<64;e++){
        float4 wv = wr[e];
#pragma unroll
        for (int r=0;r<15;r++){
            float4 sv = s4[r*64+e];
            acc[r] += sv.x*wv.x + sv.y*wv.y + sv.z*wv.z + sv.w*wv.w;
        }
    }
#pragma unroll
    for (int r=0;r<15;r++) qbf[(size_t)b*4096 + r*256 + c] = f2bf(acc[r]);
    qbf[(size_t)b*4096 + 15*256 + c] = 0;
}

// ---------------- fused attention pass (MFMA) ----------------
// phase 2: each wave owns a distinct 64-wide d-range and loops all 4 n-windows
// -> no cross-wave accumulation, no LDS atomics, no updR buffer.
__global__ __launch_bounds__(256) void k_attn(const unsigned short* __restrict__ kbuf,
                                              const unsigned short* __restrict__ vT,
                                              const unsigned short* __restrict__ qbf,
                                              float* __restrict__ part, float* __restrict__ asum){
    __shared__ unsigned short qls[16*264];
    __shared__ unsigned short atn[4][16*72];
    __shared__ float asl[16];
    int tid = threadIdx.x;
    int w = tid >> 6, l = tid & 63;
    int b = blockIdx.y, n0 = blockIdx.x*256;
    if (tid < 16) asl[tid] = 0.f;
    {
        const short8* qg = (const short8*)(qbf + (size_t)b*4096);
        for (int i = tid; i < 512; i += 256){
            int row = i >> 5, cc = i & 31;
            *(short8*)&qls[row*264 + cc*8] = qg[i];
        }
    }
    __syncthreads();
    int lr = l & 15, lg = l >> 4;
    // phase 1: logits 16s x 64n per wave
    f32x4 acc[4];
#pragma unroll
    for (int t=0;t<4;t++) acc[t] = (f32x4){0.f,0.f,0.f,0.f};
    const unsigned short* kb = kbuf + ((size_t)(b*Nn) + n0 + w*64)*256;
#pragma unroll
    for (int ks=0; ks<8; ks++){
        short8 af = *(const short8*)&qls[lr*264 + ks*32 + lg*8];
#pragma unroll
        for (int t=0;t<4;t++){
            short8 bf = *(const short8*)(kb + ((size_t)(t*16+lr))*256 + ks*32 + lg*8);
            acc[t] = __builtin_amdgcn_mfma_f32_16x16x32_bf16(af, bf, acc[t], 0,0,0);
        }
    }
    // softmax over slots (per column n), write attn to LDS (bf16, A-layout ready)
    float asr[4] = {0.f,0.f,0.f,0.f};
#pragma unroll
    for (int t=0;t<4;t++){
        float v0=acc[t][0], v1=acc[t][1], v2=acc[t][2], v3=acc[t][3];
        if (lg==3) v3 = -1e30f;
        float m = fmaxf(fmaxf(v0,v1), fmaxf(v2,v3));
        m = fmaxf(m, __shfl_xor(m,16));
        m = fmaxf(m, __shfl_xor(m,32));
        float e0=__expf((v0-m)*0.0625f), e1=__expf((v1-m)*0.0625f),
              e2=__expf((v2-m)*0.0625f), e3=(lg==3)?0.f:__expf((v3-m)*0.0625f);
        float s = e0+e1+e2+e3;
        s += __shfl_xor(s,16); s += __shfl_xor(s,32);
        float inv = 1.f/s;
        e0*=inv; e1*=inv; e2*=inv; e3*=inv;
        unsigned short* a_ = &atn[w][0];
        int col = t*16 + lr;
        a_[(lg*4+0)*72+col] = f2bf(e0);
        a_[(lg*4+1)*72+col] = f2bf(e1);
        a_[(lg*4+2)*72+col] = f2bf(e2);
        a_[(lg*4+3)*72+col] = f2bf(e3);
        float p0=e0,p1=e1,p2=e2,p3=e3;
        for (int mk=1;mk<16;mk<<=1){
            p0+=__shfl_xor(p0,mk); p1+=__shfl_xor(p1,mk);
            p2+=__shfl_xor(p2,mk); p3+=__shfl_xor(p3,mk);
        }
        asr[0]+=p0; asr[1]+=p1; asr[2]+=p2; asr[3]+=p3;
    }
    if (lr == 0){
        atomicAdd(&asl[lg*4+0], asr[0]);
        atomicAdd(&asl[lg*4+1], asr[1]);
        atomicAdd(&asl[lg*4+2], asr[2]);
        atomicAdd(&asl[lg*4+3], asr[3]);
    }
    __syncthreads();   // atn[*] + asl complete
    // phase 2: wave w owns d-range [w*64, w*64+64); loops all 4 n-windows
    f32x4 ua[4];
#pragma unroll
    for (int dt=0;dt<4;dt++) ua[dt] = (f32x4){0.f,0.f,0.f,0.f};
    const unsigned short* vb = vT + (size_t)b*256*4096 + ((size_t)(w*64 + lr))*4096 + n0 + lg*8;
#pragma unroll
    for (int wn=0;wn<4;wn++)
#pragma unroll
        for (int kc=0;kc<2;kc++){
            short8 af = *(const short8*)&atn[wn][lr*72 + kc*32 + lg*8];
#pragma unroll
            for (int dt=0;dt<4;dt++){
                short8 bf = *(const short8*)(vb + (size_t)dt*16*4096 + wn*64 + kc*32);
                ua[dt] = __builtin_amdgcn_mfma_f32_16x16x32_bf16(af, bf, ua[dt], 0,0,0);
            }
        }
    float* pb = part + ((size_t)(b*16 + blockIdx.x))*4096;
#pragma unroll
    for (int dt=0;dt<4;dt++)
#pragma unroll
        for (int r=0;r<4;r++)
            pb[(lg*4+r)*256 + w*64 + dt*16 + lr] = ua[dt][r];
    if (tid < 15) atomicAdd(&asum[b*15+tid], asl[tid]);
}

__global__ __launch_bounds__(256) void k_upd_reduce(const float* __restrict__ part, float* __restrict__ upd){
    int i = blockIdx.x*256 + threadIdx.x;   // < 245760
    int b = i / 3840, rem = i - b*3840;
    const float* p = part + (size_t)b*16*4096 + rem;
    float s = 0.f;
#pragma unroll
    for (int j=0;j<16;j++) s += p[j*4096];
    upd[i] = s;
}

// ---------------- GRU gates ----------------
__global__ __launch_bounds__(256) void k_gates(const float* __restrict__ upd, const float* __restrict__ asum,
                                               const float* __restrict__ S,
                                               const float* __restrict__ wih, const float* __restrict__ whh,
                                               const float* __restrict__ bih, const float* __restrict__ bhh,
                                               float* __restrict__ gates){
    int b = blockIdx.y;
    int c = blockIdx.x*256 + threadIdx.x;
    bool isGI = (c < 768);
    const float* wrow = isGI ? (wih + (size_t)c*256) : (whh + (size_t)(c-768)*256);
    const float* src  = isGI ? (upd + (size_t)b*Kk*Dd) : (S + (size_t)b*Kk*Dd);
    float bias = isGI ? bih[c] : bhh[c-768];
    const float4* w4 = (const float4*)wrow;
    const float4* s4 = (const float4*)src;
    float acc[15];
#pragma unroll
    for (int r=0;r<15;r++) acc[r] = 0.f;
    for (int e=0;e<64;e++){
        float4 wv = w4[e];
#pragma unroll
        for (int r=0;r<15;r++){
            float4 sv = s4[r*64+e];
            acc[r] += sv.x*wv.x + sv.y*wv.y + sv.z*wv.z + sv.w*wv.w;
        }
    }
#pragma unroll
    for (int r=0;r<15;r++){
        float v = acc[r];
        if (isGI) v *= 1.f/(asum[b*Kk+r] + EPSN);
        gates[((size_t)(b*Kk+r))*1536 + c] = v + bias;
    }
}

__global__ __launch_bounds__(256) void k_gru(const float* __restrict__ gates, const float* __restrict__ S,
                                             float* __restrict__ G){
    int row = blockIdx.x, d = threadIdx.x;
    const float* gr = gates + (size_t)row*1536;
    float ir=gr[d], iz=gr[256+d], inn=gr[512+d];
    float hr=gr[768+d], hz=gr[1024+d], hn=gr[1280+d];
    float r = sigm_(ir+hr), z = sigm_(iz+hz);
    float n = tanh_(inn + r*hn);
    float h = S[(size_t)row*Dd + d];
    G[(size_t)row*Dd + d] = (1.f-z)*n + z*h;
}

__global__ __launch_bounds__(256) void k_mlp1(const float* __restrict__ sn, const float* __restrict__ w1,
                                              const float* __restrict__ b1, float* __restrict__ h1){
    int b = blockIdx.y;
    int c = blockIdx.x*256 + threadIdx.x;
    const float4* w4 = (const float4*)(w1 + (size_t)c*256);
    const float4* s4 = (const float4*)(sn + (size_t)b*Kk*Dd);
    float acc[15];
#pragma unroll
    for (int r=0;r<15;r++) acc[r] = 0.f;
    for (int e=0;e<64;e++){
        float4 wv = w4[e];
#pragma unroll
        for (int r=0;r<15;r++){
            float4 sv = s4[r*64+e];
            acc[r] += sv.x*wv.x + sv.y*wv.y + sv.z*wv.z + sv.w*wv.w;
        }
    }
    float bias = b1[c];
#pragma unroll
    for (int r=0;r<15;r++)
        h1[((size_t)(b*Kk+r))*Hh + c] = fmaxf(acc[r] + bias, 0.f);
}

__global__ __launch_bounds__(256) void k_mlp2(const float* __restrict__ G, const float* __restrict__ h1,
                                              const float* __restrict__ w2, const float* __restrict__ b2,
                                              float* __restrict__ S){
    int b = blockIdx.x, c = threadIdx.x;
    const float4* w4 = (const float4*)(w2 + (size_t)c*512);
    const float4* h4 = (const float4*)(h1 + (size_t)b*Kk*Hh);
    float acc[15];
#pragma unroll
    for (int r=0;r<15;r++) acc[r] = 0.f;
    for (int e=0;e<128;e++){
        float4 wv = w4[e];
#pragma unroll
        for (int r=0;r<15;r++){
            float4 hv = h4[r*128+e];
            acc[r] += hv.x*wv.x + hv.y*wv.y + hv.z*wv.z + hv.w*wv.w;
        }
    }
    float bias = b2[c];
#pragma unroll
    for (int r=0;r<15;r++){
        size_t i = ((size_t)(b*Kk+r))*Dd + c;
        S[i] = G[i] + acc[r] + bias;
    }
}

// ---------------- final attention output (MFMA logits + softmax) ----------------
__global__ __launch_bounds__(256) void k_attn_out(const unsigned short* __restrict__ kbuf,
                                                  const unsigned short* __restrict__ qbf,
                                                  float* __restrict__ out){
    __shared__ unsigned short qls[16*264];
    int tid = threadIdx.x;
    int w = tid >> 6, l = tid & 63;
    int b = blockIdx.y, n0 = blockIdx.x*256;
    {
        const short8* qg = (const short8*)(qbf + (size_t)b*4096);
        for (int i = tid; i < 512; i += 256){
            int row = i >> 5, cc = i & 31;
            *(short8*)&qls[row*264 + cc*8] = qg[i];
        }
    }
    __syncthreads();
    int lr = l & 15, lg = l >> 4;
    f32x4 acc[4];
#pragma unroll
    for (int t=0;t<4;t++) acc[t] = (f32x4){0.f,0.f,0.f,0.f};
    const unsigned short* kb = kbuf + ((size_t)(b*Nn) + n0 + w*64)*256;
#pragma unroll
    for (int ks=0; ks<8; ks++){
        short8 af = *(const short8*)&qls[lr*264 + ks*32 + lg*8];
#pragma unroll
        for (int t=0;t<4;t++){
            short8 bf = *(const short8*)(kb + ((size_t)(t*16+lr))*256 + ks*32 + lg*8);
            acc[t] = __builtin_amdgcn_mfma_f32_16x16x32_bf16(af, bf, acc[t], 0,0,0);
        }
    }
#pragma unroll
    for (int t=0;t<4;t++){
        float v0=acc[t][0], v1=acc[t][1], v2=acc[t][2], v3=acc[t][3];
        if (lg==3) v3 = -1e30f;
        float m = fmaxf(fmaxf(v0,v1), fmaxf(v2,v3));
        m = fmaxf(m, __shfl_xor(m,16));
        m = fmaxf(m, __shfl_xor(m,32));
        float e0=__expf((v0-m)*0.0625f), e1=__expf((v1-m)*0.0625f),
              e2=__expf((v2-m)*0.0625f), e3=(lg==3)?0.f:__expf((v3-m)*0.0625f);
        float s = e0+e1+e2+e3;
        s += __shfl_xor(s,16); s += __shfl_xor(s,32);
        float inv = 1.f/s;
        int n = n0 + w*64 + t*16 + lr;
        float ee0=e0*inv, ee1=e1*inv, ee2=e2*inv, ee3=e3*inv;
        out[((size_t)(b*15 + lg*4+0))*4096 + n] = ee0;
        out[((size_t)(b*15 + lg*4+1))*4096 + n] = ee1;
        out[((size_t)(b*15 + lg*4+2))*4096 + n] = ee2;
        if (lg != 3) out[((size_t)(b*15 + lg*4+3))*4096 + n] = ee3;
    }
}

__global__ __launch_bounds__(256) void k_copy(const float* __restrict__ src, float* __restrict__ dst){
    int i = blockIdx.x*256 + threadIdx.x;
    dst[i] = src[i];
}

extern "C" void kernel_launch(void* const* d_in, const int* in_sizes, int n_in,
                              void* d_out, int out_size, void* d_ws, size_t ws_size,
                              hipStream_t stream) {
    const float* inputs = (const float*)d_in[0];
    const float* noise  = (const float*)d_in[1];
    const float* mu     = (const float*)d_in[2];
    const float* lsig   = (const float*)d_in[3];
    const float* Wq     = (const float*)d_in[4];
    const float* Wk     = (const float*)d_in[5];
    const float* Wv     = (const float*)d_in[6];
    const float* wih    = (const float*)d_in[7];
    const float* whh    = (const float*)d_in[8];
    const float* bih    = (const float*)d_in[9];
    const float* bhh    = (const float*)d_in[10];
    const float* w1     = (const float*)d_in[11];
    const float* b1     = (const float*)d_in[12];
    const float* w2     = (const float*)d_in[13];
    const float* b2     = (const float*)d_in[14];
    const float* lin_w  = (const float*)d_in[15];
    const float* lin_b  = (const float*)d_in[16];
    const float* lsl_w  = (const float*)d_in[17];
    const float* lsl_b  = (const float*)d_in[18];
    const float* lml_w  = (const float*)d_in[19];
    const float* lml_b  = (const float*)d_in[20];

    char* ws = (char*)d_ws;
    unsigned short* xbf  = (unsigned short*)(ws + OFF_X);
    float*          PART = (float*)(ws + OFF_X);       // aliases xbf (dead after k_proj)
    unsigned short* kbuf = (unsigned short*)(ws + OFF_K);
    unsigned short* vT   = (unsigned short*)(ws + OFF_VT);
    unsigned short* wc   = (unsigned short*)(ws + OFF_WC);
    unsigned short* QBF  = (unsigned short*)(ws + OFF_QBF);
    float* S    = (float*)(ws + OFF_S);
    float* G    = (float*)(ws + OFF_G);
    float* SN   = (float*)(ws + OFF_SN);
    float* UPD  = (float*)(ws + OFF_UPD);
    float* ASUM = (float*)(ws + OFF_ASUM);
    float* GT   = (float*)(ws + OFF_GT);
    float* H1   = (float*)(ws + OFF_H1);
    float* out  = (float*)d_out;

    k_prep_wc<<<512, 256, 0, stream>>>(Wk, Wv, wc);
    k_slots_init<<<960, 256, 0, stream>>>(mu, lsig, noise, S);
    k_ln_in<<<BN/4, 256, 0, stream>>>(inputs, lin_w, lin_b, xbf);
    k_proj<<<BN/128, 512, 0, stream>>>(xbf, wc, kbuf, vT);

    for (int it = 0; it < 3; it++){
        k_ln_rows<<<240, 256, 0, stream>>>(S, lsl_w, lsl_b, SN);
        k_q<<<Bh, 256, 0, stream>>>(SN, Wq, QBF);
        hipMemsetAsync(ASUM, 0, 4096, stream);
        k_attn<<<dim3(16, Bh), 256, 0, stream>>>(kbuf, vT, QBF, PART, ASUM);
        k_upd_reduce<<<960, 256, 0, stream>>>(PART, UPD);
        k_gates<<<dim3(6, Bh), 256, 0, stream>>>(UPD, ASUM, S, wih, whh, bih, bhh, GT);
        k_gru<<<960, 256, 0, stream>>>(GT, S, G);
        k_ln_rows<<<240, 256, 0, stream>>>(G, lml_w, lml_b, SN);
        k_mlp1<<<dim3(2, Bh), 256, 0, stream>>>(SN, w1, b1, H1);
        k_mlp2<<<Bh, 256, 0, stream>>>(G, H1, w2, b2, S);
    }

    k_ln_rows<<<240, 256, 0, stream>>>(S, lsl_w, lsl_b, SN);
    k_q<<<Bh, 256, 0, stream>>>(SN, Wq, QBF);
    k_attn_out<<<dim3(16, Bh), 256, 0, stream>>>(kbuf, QBF, out + 245760);
    k_copy<<<960, 256, 0, stream>>>(S, out);
}

// Round 4
// 1407.011 us; speedup vs baseline: 1.4363x; 1.4363x over previous
//
#include <hip/hip_runtime.h>
#include <hip/hip_bf16.h>
#include <stdint.h>

#define Bh 64
#define Nn 4096
#define Dd 256
#define Kk 15
#define Hh 512
#define BN (Bh*Nn)
#define EPSN 1e-8f
#define LN_EPS 1e-5f

typedef __attribute__((ext_vector_type(8))) short short8;
typedef __attribute__((ext_vector_type(4))) float f32x4;

__device__ __forceinline__ float bflo(unsigned u){ return __uint_as_float(u << 16); }
__device__ __forceinline__ float bfhi(unsigned u){ return __uint_as_float(u & 0xffff0000u); }
__device__ __forceinline__ unsigned short f2bf(float f){
    unsigned b = __float_as_uint(f);
    b += 0x7fffu + ((b >> 16) & 1u);   // RNE
    return (unsigned short)(b >> 16);
}
__device__ __forceinline__ float sigm_(float x){ return 1.f/(1.f+__expf(-x)); }
__device__ __forceinline__ float tanh_(float x){ return 1.f - 2.f/(__expf(2.f*x)+1.f); }

__device__ __forceinline__ void async16(const void* g, void* l){
    __builtin_amdgcn_global_load_lds((const __attribute__((address_space(1))) void*)g,
                                     (__attribute__((address_space(3))) void*)l, 16, 0, 0);
}

// ---------------- workspace layout (bytes) ----------------
// PART aliases xbf (xbf dead after k_proj)
#define OFF_X    ((size_t)0)                         // xbf 134217728 ; PART (16.7MB) aliases
#define OFF_K    (OFF_X  + (size_t)BN*256*2)         // k bf16 rows of 256
#define OFF_VT   (OFF_K  + (size_t)BN*256*2)         // vT bf16 [b][256][4096]
#define OFF_WC   (OFF_VT + (size_t)BN*256*2)         // Wc bf16 512*256
#define OFF_QBF  (OFF_WC + (size_t)512*256*2)        // q bf16 [b][16][256]
#define OFF_S    (OFF_QBF+ (size_t)64*16*256*2)
#define OFF_G    (OFF_S  + (size_t)983040)
#define OFF_SN   (OFF_G  + (size_t)983040)
#define OFF_UPD  (OFF_SN + (size_t)983040)
#define OFF_ASUM (OFF_UPD+ (size_t)983040)           // 4096
#define OFF_GT   (OFF_ASUM+(size_t)4096)
#define OFF_H1   (OFF_GT + (size_t)960*1536*4)

// ---------------- prep ----------------
__global__ __launch_bounds__(256) void k_prep_wc(const float* __restrict__ Wk, const float* __restrict__ Wv,
                                                 unsigned short* __restrict__ Wc){
    int i = blockIdx.x*256 + threadIdx.x;
    int n = i >> 8, e = i & 255;
    float w = (n < 256) ? Wk[n*256+e] : Wv[(n-256)*256+e];
    Wc[i] = f2bf(w);
}

__global__ __launch_bounds__(256) void k_slots_init(const float* __restrict__ mu, const float* __restrict__ lsig,
                                                    const float* __restrict__ noise, float* __restrict__ S){
    int i = blockIdx.x*256 + threadIdx.x;
    int j = i % (Kk*Dd);
    S[i] = mu[j] + __expf(lsig[j]) * noise[i];
}

__global__ __launch_bounds__(256) void k_ln_in(const float* __restrict__ x, const float* __restrict__ g,
                                               const float* __restrict__ b, unsigned short* __restrict__ out){
    int wave = threadIdx.x >> 6, lane = threadIdx.x & 63;
    size_t row = (size_t)blockIdx.x*4 + wave;
    const float4* xr = (const float4*)(x + row*Dd);
    float4 v = xr[lane];
    float s  = v.x+v.y+v.z+v.w;
    float ss = v.x*v.x+v.y*v.y+v.z*v.z+v.w*v.w;
    for (int m=1;m<64;m<<=1){ s += __shfl_xor(s,m); ss += __shfl_xor(ss,m); }
    float mean = s*(1.f/Dd);
    float rstd = rsqrtf(ss*(1.f/Dd) - mean*mean + LN_EPS);
    float4 gv = ((const float4*)g)[lane], bv = ((const float4*)b)[lane];
    ushort4 o;
    o.x = f2bf((v.x-mean)*rstd*gv.x + bv.x);
    o.y = f2bf((v.y-mean)*rstd*gv.y + bv.y);
    o.z = f2bf((v.z-mean)*rstd*gv.z + bv.z);
    o.w = f2bf((v.w-mean)*rstd*gv.w + bv.w);
    *(ushort4*)(out + row*Dd + lane*4) = o;
}

__global__ __launch_bounds__(256) void k_ln_rows(const float* __restrict__ x, const float* __restrict__ g,
                                                 const float* __restrict__ b, float* __restrict__ out){
    int wave = threadIdx.x >> 6, lane = threadIdx.x & 63;
    size_t row = (size_t)blockIdx.x*4 + wave;
    const float4* xr = (const float4*)(x + row*Dd);
    float4 v = xr[lane];
    float s  = v.x+v.y+v.z+v.w;
    float ss = v.x*v.x+v.y*v.y+v.z*v.z+v.w*v.w;
    for (int m=1;m<64;m<<=1){ s += __shfl_xor(s,m); ss += __shfl_xor(ss,m); }
    float mean = s*(1.f/Dd);
    float rstd = rsqrtf(ss*(1.f/Dd) - mean*mean + LN_EPS);
    float4 gv = ((const float4*)g)[lane], bv = ((const float4*)b)[lane];
    float4 o;
    o.x = (v.x-mean)*rstd*gv.x + bv.x;
    o.y = (v.y-mean)*rstd*gv.y + bv.y;
    o.z = (v.z-mean)*rstd*gv.z + bv.z;
    o.w = (v.w-mean)*rstd*gv.w + bv.w;
    *(float4*)(out + row*Dd + lane*4) = o;
}

// ---------------- MFMA projection: [k | vT] = LN(x)_bf16 @ [Wk;Wv]^T ----------------
// A-panel-resident + hand-unrolled depth-2 register pipeline for B.
// __launch_bounds__(512, 2): 2 blocks/CU (LDS-bound anyway) -> 128-VGPR budget.
// (512,4) was capping at 64 VGPRs on this toolchain -> wholesale scratch spill.
__global__ __launch_bounds__(512, 2) void k_proj(const unsigned short* __restrict__ A,
                                                 const unsigned short* __restrict__ Bw,
                                                 unsigned short* __restrict__ kb,
                                                 unsigned short* __restrict__ vT){
    __shared__ short As[128*256];   // 64 KB: rows of 32 chunks(16B), chunk' = chunk ^ (row&7)
    int tid = threadIdx.x;
    int w = tid >> 6, lane = tid & 63;
    int m0 = blockIdx.x*128;
    int wr = w >> 2, wc = w & 3;           // 8 waves: 2 (rows) x 4 (cols)
    int lr = lane & 15, lg = lane >> 4;

    // stage A panel: 8 rounds x 512 threads x 16B, source pre-swizzled (both-sides rule)
#pragma unroll
    for (int j=0;j<8;j++){
        int idx = j*512 + tid;            // 0..4095
        int row = idx >> 5, chp = idx & 31;
        int ch  = chp ^ (row & 7);        // involution
        async16((const char*)A + ((size_t)(m0+row)*256 + ch*8)*2, (char*)As + (size_t)idx*16);
    }

    const unsigned short* bwl = Bw + (size_t)(wc*32 + lr)*256 + lg*8;

    // unit t (0..15): nt=t>>2, hf=(t>>1)&1, u=t&1 ; covers ks = hf*4+u*2+{0,1}, ni={0,1}
    short8 A_0,A_1,A_2,A_3, B_0,B_1,B_2,B_3, C_0,C_1,C_2,C_3;
    f32x4 acc00,acc01,acc10,acc11,acc20,acc21,acc30,acc31;

#define ISSUE(P, t_) { \
    const unsigned short* bp_ = bwl + ((t_)>>2)*32768 + (((t_)>>1)&1)*128 + ((t_)&1)*64; \
    P##0 = *(const short8*)(bp_); \
    P##1 = *(const short8*)(bp_ + 32); \
    P##2 = *(const short8*)(bp_ + 4096); \
    P##3 = *(const short8*)(bp_ + 4096 + 32); }
#define LDA(mi_, ks_) (*(const short8*)((const char*)As + (wr*64 + (mi_)*16 + lr)*512 + ((((ks_)*4+lg))^swz)*16))
#define MF(a_,b_,c_) __builtin_amdgcn_mfma_f32_16x16x32_bf16(a_,b_,c_,0,0,0)
#define COMPQ(F0, F1, ks_) { \
    short8 af0=LDA(0,ks_), af1=LDA(1,ks_), af2=LDA(2,ks_), af3=LDA(3,ks_); \
    acc00=MF(af0,F0,acc00); acc01=MF(af0,F1,acc01); \
    acc10=MF(af1,F0,acc10); acc11=MF(af1,F1,acc11); \
    acc20=MF(af2,F0,acc20); acc21=MF(af2,F1,acc21); \
    acc30=MF(af3,F0,acc30); acc31=MF(af3,F1,acc31); }
#define COMPU(P, t_) { COMPQ(P##0, P##2, ((((t_)>>1)&1)*4 + ((t_)&1)*2 + 0)); \
                       COMPQ(P##1, P##3, ((((t_)>>1)&1)*4 + ((t_)&1)*2 + 1)); }
#define ZERO { acc00=acc01=acc10=acc11=acc20=acc21=acc30=acc31=(f32x4){0.f,0.f,0.f,0.f}; }
#define STK(nt_, mi_, ni_, A_) { \
    int gn_ = (nt_)*128 + wc*32 + (ni_)*16 + cn; \
    _Pragma("unroll") for (int r=0;r<4;r++){ \
        size_t gm_ = (size_t)m0 + wr*64 + (mi_)*16 + cr + r; \
        kb[gm_*256 + gn_] = f2bf(A_[r]); } }
#define STV(nt_, mi_, ni_, A_) { \
    int nl_ = nl0 + wr*64 + (mi_)*16 + cr; \
    int d_  = ((nt_)-2)*128 + wc*32 + (ni_)*16 + cn; \
    ushort4 o_; o_.x=f2bf(A_[0]); o_.y=f2bf(A_[1]); o_.z=f2bf(A_[2]); o_.w=f2bf(A_[3]); \
    *(ushort4*)(vT + ((size_t)bb*256 + d_)*4096 + nl_) = o_; }
#define EPI_K(nt_) { STK(nt_,0,0,acc00) STK(nt_,0,1,acc01) STK(nt_,1,0,acc10) STK(nt_,1,1,acc11) \
                     STK(nt_,2,0,acc20) STK(nt_,2,1,acc21) STK(nt_,3,0,acc30) STK(nt_,3,1,acc31) }
#define EPI_V(nt_) { STV(nt_,0,0,acc00) STV(nt_,0,1,acc01) STV(nt_,1,0,acc10) STV(nt_,1,1,acc11) \
                     STV(nt_,2,0,acc20) STV(nt_,2,1,acc21) STV(nt_,3,0,acc30) STV(nt_,3,1,acc31) }

    ISSUE(A_,0) ISSUE(B_,1) ISSUE(C_,2)
    __syncthreads();                       // single barrier; drains staging (and first units)

    int bb  = m0 >> 12;                    // batch (128 | 4096 so constant per block)
    int nl0 = m0 & 4095;
    int cn = lr, cr = lg*4;
    int swz = lr & 7;

    ZERO
    COMPU(A_,0)  ISSUE(A_,3)
    COMPU(B_,1)  ISSUE(B_,4)
    COMPU(C_,2)  ISSUE(C_,5)
    COMPU(A_,3)  ISSUE(A_,6)
    EPI_K(0) ZERO
    COMPU(B_,4)  ISSUE(B_,7)
    COMPU(C_,5)  ISSUE(C_,8)
    COMPU(A_,6)  ISSUE(A_,9)
    COMPU(B_,7)  ISSUE(B_,10)
    EPI_K(1) ZERO
    COMPU(C_,8)  ISSUE(C_,11)
    COMPU(A_,9)  ISSUE(A_,12)
    COMPU(B_,10) ISSUE(B_,13)
    COMPU(C_,11) ISSUE(C_,14)
    EPI_V(2) ZERO
    COMPU(A_,12) ISSUE(A_,15)
    COMPU(B_,13)
    COMPU(C_,14)
    COMPU(A_,15)
    EPI_V(3)

#undef ISSUE
#undef LDA
#undef MF
#undef COMPQ
#undef COMPU
#undef ZERO
#undef STK
#undef STV
#undef EPI_K
#undef EPI_V
}

// ---------------- q = LN(slots) @ Wq^T -> bf16 [b][16][256] ----------------
__global__ __launch_bounds__(256) void k_q(const float* __restrict__ sn, const float* __restrict__ Wq,
                                           unsigned short* __restrict__ qbf){
    int b = blockIdx.x, c = threadIdx.x;
    const float4* wr = (const float4*)(Wq + (size_t)c*256);
    const float4* s4 = (const float4*)(sn + (size_t)b*Kk*Dd);
    float acc[15];
#pragma unroll
    for (int r=0;r<15;r++) acc[r] = 0.f;
    for (int e=0;e<64;e++){
        float4 wv = wr[e];
#pragma unroll
        for (int r=0;r<15;r++){
            float4 sv = s4[r*64+e];
            acc[r] += sv.x*wv.x + sv.y*wv.y + sv.z*wv.z + sv.w*wv.w;
        }
    }
#pragma unroll
    for (int r=0;r<15;r++) qbf[(size_t)b*4096 + r*256 + c] = f2bf(acc[r]);
    qbf[(size_t)b*4096 + 15*256 + c] = 0;
}

// ---------------- fused attention pass (MFMA) ----------------
// phase 2: each wave owns a distinct 64-wide d-range and loops all 4 n-windows
// -> no cross-wave accumulation, no LDS atomics, no updR buffer.
__global__ __launch_bounds__(256) void k_attn(const unsigned short* __restrict__ kbuf,
                                              const unsigned short* __restrict__ vT,
                                              const unsigned short* __restrict__ qbf,
                                              float* __restrict__ part, float* __restrict__ asum){
    __shared__ unsigned short qls[16*264];
    __shared__ unsigned short atn[4][16*72];
    __shared__ float asl[16];
    int tid = threadIdx.x;
    int w = tid >> 6, l = tid & 63;
    int b = blockIdx.y, n0 = blockIdx.x*256;
    if (tid < 16) asl[tid] = 0.f;
    {
        const short8* qg = (const short8*)(qbf + (size_t)b*4096);
        for (int i = tid; i < 512; i += 256){
            int row = i >> 5, cc = i & 31;
            *(short8*)&qls[row*264 + cc*8] = qg[i];
        }
    }
    __syncthreads();
    int lr = l & 15, lg = l >> 4;
    // phase 1: logits 16s x 64n per wave
    f32x4 acc[4];
#pragma unroll
    for (int t=0;t<4;t++) acc[t] = (f32x4){0.f,0.f,0.f,0.f};
    const unsigned short* kb = kbuf + ((size_t)(b*Nn) + n0 + w*64)*256;
#pragma unroll
    for (int ks=0; ks<8; ks++){
        short8 af = *(const short8*)&qls[lr*264 + ks*32 + lg*8];
#pragma unroll
        for (int t=0;t<4;t++){
            short8 bf = *(const short8*)(kb + ((size_t)(t*16+lr))*256 + ks*32 + lg*8);
            acc[t] = __builtin_amdgcn_mfma_f32_16x16x32_bf16(af, bf, acc[t], 0,0,0);
        }
    }
    // softmax over slots (per column n), write attn to LDS (bf16, A-layout ready)
    float asr[4] = {0.f,0.f,0.f,0.f};
#pragma unroll
    for (int t=0;t<4;t++){
        float v0=acc[t][0], v1=acc[t][1], v2=acc[t][2], v3=acc[t][3];
        if (lg==3) v3 = -1e30f;
        float m = fmaxf(fmaxf(v0,v1), fmaxf(v2,v3));
        m = fmaxf(m, __shfl_xor(m,16));
        m = fmaxf(m, __shfl_xor(m,32));
        float e0=__expf((v0-m)*0.0625f), e1=__expf((v1-m)*0.0625f),
              e2=__expf((v2-m)*0.0625f), e3=(lg==3)?0.f:__expf((v3-m)*0.0625f);
        float s = e0+e1+e2+e3;
        s += __shfl_xor(s,16); s += __shfl_xor(s,32);
        float inv = 1.f/s;
        e0*=inv; e1*=inv; e2*=inv; e3*=inv;
        unsigned short* a_ = &atn[w][0];
        int col = t*16 + lr;
        a_[(lg*4+0)*72+col] = f2bf(e0);
        a_[(lg*4+1)*72+col] = f2bf(e1);
        a_[(lg*4+2)*72+col] = f2bf(e2);
        a_[(lg*4+3)*72+col] = f2bf(e3);
        float p0=e0,p1=e1,p2=e2,p3=e3;
        for (int mk=1;mk<16;mk<<=1){
            p0+=__shfl_xor(p0,mk); p1+=__shfl_xor(p1,mk);
            p2+=__shfl_xor(p2,mk); p3+=__shfl_xor(p3,mk);
        }
        asr[0]+=p0; asr[1]+=p1; asr[2]+=p2; asr[3]+=p3;
    }
    if (lr == 0){
        atomicAdd(&asl[lg*4+0], asr[0]);
        atomicAdd(&asl[lg*4+1], asr[1]);
        atomicAdd(&asl[lg*4+2], asr[2]);
        atomicAdd(&asl[lg*4+3], asr[3]);
    }
    __syncthreads();   // atn[*] + asl complete
    // phase 2: wave w owns d-range [w*64, w*64+64); loops all 4 n-windows
    f32x4 ua[4];
#pragma unroll
    for (int dt=0;dt<4;dt++) ua[dt] = (f32x4){0.f,0.f,0.f,0.f};
    const unsigned short* vb = vT + (size_t)b*256*4096 + ((size_t)(w*64 + lr))*4096 + n0 + lg*8;
#pragma unroll
    for (int wn=0;wn<4;wn++)
#pragma unroll
        for (int kc=0;kc<2;kc++){
            short8 af = *(const short8*)&atn[wn][lr*72 + kc*32 + lg*8];
#pragma unroll
            for (int dt=0;dt<4;dt++){
                short8 bf = *(const short8*)(vb + (size_t)dt*16*4096 + wn*64 + kc*32);
                ua[dt] = __builtin_amdgcn_mfma_f32_16x16x32_bf16(af, bf, ua[dt], 0,0,0);
            }
        }
    float* pb = part + ((size_t)(b*16 + blockIdx.x))*4096;
#pragma unroll
    for (int dt=0;dt<4;dt++)
#pragma unroll
        for (int r=0;r<4;r++)
            pb[(lg*4+r)*256 + w*64 + dt*16 + lr] = ua[dt][r];
    if (tid < 15) atomicAdd(&asum[b*15+tid], asl[tid]);
}

__global__ __launch_bounds__(256) void k_upd_reduce(const float* __restrict__ part, float* __restrict__ upd){
    int i = blockIdx.x*256 + threadIdx.x;   // < 245760
    int b = i / 3840, rem = i - b*3840;
    const float* p = part + (size_t)b*16*4096 + rem;
    float s = 0.f;
#pragma unroll
    for (int j=0;j<16;j++) s += p[j*4096];
    upd[i] = s;
}

// ---------------- GRU gates ----------------
__global__ __launch_bounds__(256) void k_gates(const float* __restrict__ upd, const float* __restrict__ asum,
                                               const float* __restrict__ S,
                                               const float* __restrict__ wih, const float* __restrict__ whh,
                                               const float* __restrict__ bih, const float* __restrict__ bhh,
                                               float* __restrict__ gates){
    int b = blockIdx.y;
    int c = blockIdx.x*256 + threadIdx.x;
    bool isGI = (c < 768);
    const float* wrow = isGI ? (wih + (size_t)c*256) : (whh + (size_t)(c-768)*256);
    const float* src  = isGI ? (upd + (size_t)b*Kk*Dd) : (S + (size_t)b*Kk*Dd);
    float bias = isGI ? bih[c] : bhh[c-768];
    const float4* w4 = (const float4*)wrow;
    const float4* s4 = (const float4*)src;
    float acc[15];
#pragma unroll
    for (int r=0;r<15;r++) acc[r] = 0.f;
    for (int e=0;e<64;e++){
        float4 wv = w4[e];
#pragma unroll
        for (int r=0;r<15;r++){
            float4 sv = s4[r*64+e];
            acc[r] += sv.x*wv.x + sv.y*wv.y + sv.z*wv.z + sv.w*wv.w;
        }
    }
#pragma unroll
    for (int r=0;r<15;r++){
        float v = acc[r];
        if (isGI) v *= 1.f/(asum[b*Kk+r] + EPSN);
        gates[((size_t)(b*Kk+r))*1536 + c] = v + bias;
    }
}

__global__ __launch_bounds__(256) void k_gru(const float* __restrict__ gates, const float* __restrict__ S,
                                             float* __restrict__ G){
    int row = blockIdx.x, d = threadIdx.x;
    const float* gr = gates + (size_t)row*1536;
    float ir=gr[d], iz=gr[256+d], inn=gr[512+d];
    float hr=gr[768+d], hz=gr[1024+d], hn=gr[1280+d];
    float r = sigm_(ir+hr), z = sigm_(iz+hz);
    float n = tanh_(inn + r*hn);
    float h = S[(size_t)row*Dd + d];
    G[(size_t)row*Dd + d] = (1.f-z)*n + z*h;
}

__global__ __launch_bounds__(256) void k_mlp1(const float* __restrict__ sn, const float* __restrict__ w1,
                                              const float* __restrict__ b1, float* __restrict__ h1){
    int b = blockIdx.y;
    int c = blockIdx.x*256 + threadIdx.x;
    const float4* w4 = (const float4*)(w1 + (size_t)c*256);
    const float4* s4 = (const float4*)(sn + (size_t)b*Kk*Dd);
    float acc[15];
#pragma unroll
    for (int r=0;r<15;r++) acc[r] = 0.f;
    for (int e=0;e<64;e++){
        float4 wv = w4[e];
#pragma unroll
        for (int r=0;r<15;r++){
            float4 sv = s4[r*64+e];
            acc[r] += sv.x*wv.x + sv.y*wv.y + sv.z*wv.z + sv.w*wv.w;
        }
    }
    float bias = b1[c];
#pragma unroll
    for (int r=0;r<15;r++)
        h1[((size_t)(b*Kk+r))*Hh + c] = fmaxf(acc[r] + bias, 0.f);
}

__global__ __launch_bounds__(256) void k_mlp2(const float* __restrict__ G, const float* __restrict__ h1,
                                              const float* __restrict__ w2, const float* __restrict__ b2,
                                              float* __restrict__ S){
    int b = blockIdx.x, c = threadIdx.x;
    const float4* w4 = (const float4*)(w2 + (size_t)c*512);
    const float4* h4 = (const float4*)(h1 + (size_t)b*Kk*Hh);
    float acc[15];
#pragma unroll
    for (int r=0;r<15;r++) acc[r] = 0.f;
    for (int e=0;e<128;e++){
        float4 wv = w4[e];
#pragma unroll
        for (int r=0;r<15;r++){
            float4 hv = h4[r*128+e];
            acc[r] += hv.x*wv.x + hv.y*wv.y + hv.z*wv.z + hv.w*wv.w;
        }
    }
    float bias = b2[c];
#pragma unroll
    for (int r=0;r<15;r++){
        size_t i = ((size_t)(b*Kk+r))*Dd + c;
        S[i] = G[i] + acc[r] + bias;
    }
}

// ---------------- final attention output (MFMA logits + softmax) ----------------
__global__ __launch_bounds__(256) void k_attn_out(const unsigned short* __restrict__ kbuf,
                                                  const unsigned short* __restrict__ qbf,
                                                  float* __restrict__ out){
    __shared__ unsigned short qls[16*264];
    int tid = threadIdx.x;
    int w = tid >> 6, l = tid & 63;
    int b = blockIdx.y, n0 = blockIdx.x*256;
    {
        const short8* qg = (const short8*)(qbf + (size_t)b*4096);
        for (int i = tid; i < 512; i += 256){
            int row = i >> 5, cc = i & 31;
            *(short8*)&qls[row*264 + cc*8] = qg[i];
        }
    }
    __syncthreads();
    int lr = l & 15, lg = l >> 4;
    f32x4 acc[4];
#pragma unroll
    for (int t=0;t<4;t++) acc[t] = (f32x4){0.f,0.f,0.f,0.f};
    const unsigned short* kb = kbuf + ((size_t)(b*Nn) + n0 + w*64)*256;
#pragma unroll
    for (int ks=0; ks<8; ks++){
        short8 af = *(const short8*)&qls[lr*264 + ks*32 + lg*8];
#pragma unroll
        for (int t=0;t<4;t++){
            short8 bf = *(const short8*)(kb + ((size_t)(t*16+lr))*256 + ks*32 + lg*8);
            acc[t] = __builtin_amdgcn_mfma_f32_16x16x32_bf16(af, bf, acc[t], 0,0,0);
        }
    }
#pragma unroll
    for (int t=0;t<4;t++){
        float v0=acc[t][0], v1=acc[t][1], v2=acc[t][2], v3=acc[t][3];
        if (lg==3) v3 = -1e30f;
        float m = fmaxf(fmaxf(v0,v1), fmaxf(v2,v3));
        m = fmaxf(m, __shfl_xor(m,16));
        m = fmaxf(m, __shfl_xor(m,32));
        float e0=__expf((v0-m)*0.0625f), e1=__expf((v1-m)*0.0625f),
              e2=__expf((v2-m)*0.0625f), e3=(lg==3)?0.f:__expf((v3-m)*0.0625f);
        float s = e0+e1+e2+e3;
        s += __shfl_xor(s,16); s += __shfl_xor(s,32);
        float inv = 1.f/s;
        int n = n0 + w*64 + t*16 + lr;
        float ee0=e0*inv, ee1=e1*inv, ee2=e2*inv, ee3=e3*inv;
        out[((size_t)(b*15 + lg*4+0))*4096 + n] = ee0;
        out[((size_t)(b*15 + lg*4+1))*4096 + n] = ee1;
        out[((size_t)(b*15 + lg*4+2))*4096 + n] = ee2;
        if (lg != 3) out[((size_t)(b*15 + lg*4+3))*4096 + n] = ee3;
    }
}

__global__ __launch_bounds__(256) void k_copy(const float* __restrict__ src, float* __restrict__ dst){
    int i = blockIdx.x*256 + threadIdx.x;
    dst[i] = src[i];
}

extern "C" void kernel_launch(void* const* d_in, const int* in_sizes, int n_in,
                              void* d_out, int out_size, void* d_ws, size_t ws_size,
                              hipStream_t stream) {
    const float* inputs = (const float*)d_in[0];
    const float* noise  = (const float*)d_in[1];
    const float* mu     = (const float*)d_in[2];
    const float* lsig   = (const float*)d_in[3];
    const float* Wq     = (const float*)d_in[4];
    const float* Wk     = (const float*)d_in[5];
    const float* Wv     = (const float*)d_in[6];
    const float* wih    = (const float*)d_in[7];
    const float* whh    = (const float*)d_in[8];
    const float* bih    = (const float*)d_in[9];
    const float* bhh    = (const float*)d_in[10];
    const float* w1     = (const float*)d_in[11];
    const float* b1     = (const float*)d_in[12];
    const float* w2     = (const float*)d_in[13];
    const float* b2     = (const float*)d_in[14];
    const float* lin_w  = (const float*)d_in[15];
    const float* lin_b  = (const float*)d_in[16];
    const float* lsl_w  = (const float*)d_in[17];
    const float* lsl_b  = (const float*)d_in[18];
    const float* lml_w  = (const float*)d_in[19];
    const float* lml_b  = (const float*)d_in[20];

    char* ws = (char*)d_ws;
    unsigned short* xbf  = (unsigned short*)(ws + OFF_X);
    float*          PART = (float*)(ws + OFF_X);       // aliases xbf (dead after k_proj)
    unsigned short* kbuf = (unsigned short*)(ws + OFF_K);
    unsigned short* vT   = (unsigned short*)(ws + OFF_VT);
    unsigned short* wc   = (unsigned short*)(ws + OFF_WC);
    unsigned short* QBF  = (unsigned short*)(ws + OFF_QBF);
    float* S    = (float*)(ws + OFF_S);
    float* G    = (float*)(ws + OFF_G);
    float* SN   = (float*)(ws + OFF_SN);
    float* UPD  = (float*)(ws + OFF_UPD);
    float* ASUM = (float*)(ws + OFF_ASUM);
    float* GT   = (float*)(ws + OFF_GT);
    float* H1   = (float*)(ws + OFF_H1);
    float* out  = (float*)d_out;

    k_prep_wc<<<512, 256, 0, stream>>>(Wk, Wv, wc);
    k_slots_init<<<960, 256, 0, stream>>>(mu, lsig, noise, S);
    k_ln_in<<<BN/4, 256, 0, stream>>>(inputs, lin_w, lin_b, xbf);
    k_proj<<<BN/128, 512, 0, stream>>>(xbf, wc, kbuf, vT);

    for (int it = 0; it < 3; it++){
        k_ln_rows<<<240, 256, 0, stream>>>(S, lsl_w, lsl_b, SN);
        k_q<<<Bh, 256, 0, stream>>>(SN, Wq, QBF);
        hipMemsetAsync(ASUM, 0, 4096, stream);
        k_attn<<<dim3(16, Bh), 256, 0, stream>>>(kbuf, vT, QBF, PART, ASUM);
        k_upd_reduce<<<960, 256, 0, stream>>>(PART, UPD);
        k_gates<<<dim3(6, Bh), 256, 0, stream>>>(UPD, ASUM, S, wih, whh, bih, bhh, GT);
        k_gru<<<960, 256, 0, stream>>>(GT, S, G);
        k_ln_rows<<<240, 256, 0, stream>>>(G, lml_w, lml_b, SN);
        k_mlp1<<<dim3(2, Bh), 256, 0, stream>>>(SN, w1, b1, H1);
        k_mlp2<<<Bh, 256, 0, stream>>>(G, H1, w2, b2, S);
    }

    k_ln_rows<<<240, 256, 0, stream>>>(S, lsl_w, lsl_b, SN);
    k_q<<<Bh, 256, 0, stream>>>(SN, Wq, QBF);
    k_attn_out<<<dim3(16, Bh), 256, 0, stream>>>(kbuf, QBF, out + 245760);
    k_copy<<<960, 256, 0, stream>>>(S, out);
}

// Round 6
// 1280.188 us; speedup vs baseline: 1.5786x; 1.0991x over previous
//
#include <hip/hip_runtime.h>
#include <hip/hip_bf16.h>
#include <stdint.h>

#define Bh 64
#define Nn 4096
#define Dd 256
#define Kk 15
#define Hh 512
#define BN (Bh*Nn)
#define EPSN 1e-8f
#define LN_EPS 1e-5f

typedef __attribute__((ext_vector_type(8))) short short8;
typedef __attribute__((ext_vector_type(4))) float f32x4;

__device__ __forceinline__ unsigned short f2bf(float f){
    unsigned b = __float_as_uint(f);
    b += 0x7fffu + ((b >> 16) & 1u);   // RNE
    return (unsigned short)(b >> 16);
}
__device__ __forceinline__ float sigm_(float x){ return 1.f/(1.f+__expf(-x)); }
__device__ __forceinline__ float tanh_(float x){ return 1.f - 2.f/(__expf(2.f*x)+1.f); }

// ---------------- workspace layout (bytes) ----------------
#define OFF_X    ((size_t)0)                         // PART (16.7MB)
#define OFF_K    (OFF_X  + (size_t)BN*256*2)         // k bf16 rows of 256
#define OFF_VT   (OFF_K  + (size_t)BN*256*2)         // vT bf16 [b][256][4096]
#define OFF_WC   (OFF_VT + (size_t)BN*256*2)         // Wc bf16 512*256
#define OFF_QBF  (OFF_WC + (size_t)512*256*2)        // q bf16 [b][16][256]
#define OFF_S    (OFF_QBF+ (size_t)64*16*256*2)
#define OFF_G    (OFF_S  + (size_t)983040)
#define OFF_SN   (OFF_G  + (size_t)983040)           // unused (kept for layout stability)
#define OFF_UPD  (OFF_SN + (size_t)983040)           // ASUMP partials (64*16*16*4 = 64KB)
#define OFF_ASUM (OFF_UPD+ (size_t)983040)           // unused
#define OFF_GT   (OFF_ASUM+(size_t)4096)
#define OFF_H1   (OFF_GT + (size_t)960*1536*4)

// ---------------- prep ----------------
__global__ __launch_bounds__(256) void k_prep_wc(const float* __restrict__ Wk, const float* __restrict__ Wv,
                                                 unsigned short* __restrict__ Wc){
    int i = blockIdx.x*256 + threadIdx.x;
    int n = i >> 8, e = i & 255;
    float w = (n < 256) ? Wk[n*256+e] : Wv[(n-256)*256+e];
    Wc[i] = f2bf(w);
}

__global__ __launch_bounds__(256) void k_slots_init(const float* __restrict__ mu, const float* __restrict__ lsig,
                                                    const float* __restrict__ noise, float* __restrict__ S){
    int i = blockIdx.x*256 + threadIdx.x;
    int j = i % (Kk*Dd);
    S[i] = mu[j] + __expf(lsig[j]) * noise[i];
}

// ---------------- MFMA projection: [k | vT] = LN(x)_bf16 @ [Wk;Wv]^T ----------------
// LN fused into staging: read raw f32 inputs, wave-parallel LN in regs,
// ds_write swizzled bf16 to the A panel. A-panel-resident, single barrier,
// hand-unrolled depth-2 register pipeline for B (all static indexing).
__global__ __launch_bounds__(512, 2) void k_proj(const float* __restrict__ X,
                                                 const float* __restrict__ lnw,
                                                 const float* __restrict__ lnb,
                                                 const unsigned short* __restrict__ Bw,
                                                 unsigned short* __restrict__ kb,
                                                 unsigned short* __restrict__ vT){
    __shared__ short As[128*256];   // 64 KB: rows of 32 chunks(16B), chunk' = chunk ^ (row&7)
    int tid = threadIdx.x;
    int w = tid >> 6, lane = tid & 63;
    int m0 = blockIdx.x*128;
    int wr = w >> 2, wc = w & 3;           // 8 waves: 2 (rows) x 4 (cols)
    int lr = lane & 15, lg = lane >> 4;

    // ---- fused LN staging: wave w stages rows [w*16, w*16+16), 2 batches of 8 ----
    {
        float4 gv = ((const float4*)lnw)[lane];
        float4 bv = ((const float4*)lnb)[lane];
        const float* xr0 = X + ((size_t)(m0 + w*16))*256 + lane*4;
#pragma unroll
        for (int bt=0; bt<2; bt++){
            float4 xv[8];
#pragma unroll
            for (int r=0;r<8;r++) xv[r] = *(const float4*)(xr0 + (size_t)(bt*8+r)*256);
#pragma unroll
            for (int r=0;r<8;r++){
                float4 v = xv[r];
                float s  = v.x+v.y+v.z+v.w;
                float ss = v.x*v.x+v.y*v.y+v.z*v.z+v.w*v.w;
                for (int mk=1;mk<64;mk<<=1){ s += __shfl_xor(s,mk); ss += __shfl_xor(ss,mk); }
                float mean = s*(1.f/256.f);
                float rstd = rsqrtf(ss*(1.f/256.f) - mean*mean + LN_EPS);
                ushort4 o;
                o.x = f2bf((v.x-mean)*rstd*gv.x + bv.x);
                o.y = f2bf((v.y-mean)*rstd*gv.y + bv.y);
                o.z = f2bf((v.z-mean)*rstd*gv.z + bv.z);
                o.w = f2bf((v.w-mean)*rstd*gv.w + bv.w);
                int row = w*16 + bt*8 + r;
                *(ushort4*)((char*)As + row*512 + (((lane>>1)^(row&7))<<4) + ((lane&1)<<3)) = o;
            }
        }
    }

    const unsigned short* bwl = Bw + (size_t)(wc*32 + lr)*256 + lg*8;

    // unit t (0..15): nt=t>>2, hf=(t>>1)&1, u=t&1 ; covers ks = hf*4+u*2+{0,1}, ni={0,1}
    short8 A_0,A_1,A_2,A_3, B_0,B_1,B_2,B_3, C_0,C_1,C_2,C_3;
    f32x4 acc00,acc01,acc10,acc11,acc20,acc21,acc30,acc31;

#define ISSUE(P, t_) { \
    const unsigned short* bp_ = bwl + ((t_)>>2)*32768 + (((t_)>>1)&1)*128 + ((t_)&1)*64; \
    P##0 = *(const short8*)(bp_); \
    P##1 = *(const short8*)(bp_ + 32); \
    P##2 = *(const short8*)(bp_ + 4096); \
    P##3 = *(const short8*)(bp_ + 4096 + 32); }
#define LDA(mi_, ks_) (*(const short8*)((const char*)As + (wr*64 + (mi_)*16 + lr)*512 + ((((ks_)*4+lg))^swz)*16))
#define MF(a_,b_,c_) __builtin_amdgcn_mfma_f32_16x16x32_bf16(a_,b_,c_,0,0,0)
#define COMPQ(F0, F1, ks_) { \
    short8 af0=LDA(0,ks_), af1=LDA(1,ks_), af2=LDA(2,ks_), af3=LDA(3,ks_); \
    acc00=MF(af0,F0,acc00); acc01=MF(af0,F1,acc01); \
    acc10=MF(af1,F0,acc10); acc11=MF(af1,F1,acc11); \
    acc20=MF(af2,F0,acc20); acc21=MF(af2,F1,acc21); \
    acc30=MF(af3,F0,acc30); acc31=MF(af3,F1,acc31); }
#define COMPU(P, t_) { COMPQ(P##0, P##2, ((((t_)>>1)&1)*4 + ((t_)&1)*2 + 0)); \
                       COMPQ(P##1, P##3, ((((t_)>>1)&1)*4 + ((t_)&1)*2 + 1)); }
#define ZERO { acc00=acc01=acc10=acc11=acc20=acc21=acc30=acc31=(f32x4){0.f,0.f,0.f,0.f}; }
#define STK(nt_, mi_, ni_, A_) { \
    int gn_ = (nt_)*128 + wc*32 + (ni_)*16 + cn; \
    _Pragma("unroll") for (int r=0;r<4;r++){ \
        size_t gm_ = (size_t)m0 + wr*64 + (mi_)*16 + cr + r; \
        kb[gm_*256 + gn_] = f2bf(A_[r]); } }
#define STV(nt_, mi_, ni_, A_) { \
    int nl_ = nl0 + wr*64 + (mi_)*16 + cr; \
    int d_  = ((nt_)-2)*128 + wc*32 + (ni_)*16 + cn; \
    ushort4 o_; o_.x=f2bf(A_[0]); o_.y=f2bf(A_[1]); o_.z=f2bf(A_[2]); o_.w=f2bf(A_[3]); \
    *(ushort4*)(vT + ((size_t)bb*256 + d_)*4096 + nl_) = o_; }
#define EPI_K(nt_) { STK(nt_,0,0,acc00) STK(nt_,0,1,acc01) STK(nt_,1,0,acc10) STK(nt_,1,1,acc11) \
                     STK(nt_,2,0,acc20) STK(nt_,2,1,acc21) STK(nt_,3,0,acc30) STK(nt_,3,1,acc31) }
#define EPI_V(nt_) { STV(nt_,0,0,acc00) STV(nt_,0,1,acc01) STV(nt_,1,0,acc10) STV(nt_,1,1,acc11) \
                     STV(nt_,2,0,acc20) STV(nt_,2,1,acc21) STV(nt_,3,0,acc30) STV(nt_,3,1,acc31) }

    ISSUE(A_,0) ISSUE(B_,1) ISSUE(C_,2)
    __syncthreads();                       // single barrier for the whole kernel

    int bb  = m0 >> 12;                    // batch (128 | 4096 so constant per block)
    int nl0 = m0 & 4095;
    int cn = lr, cr = lg*4;
    int swz = lr & 7;

    ZERO
    COMPU(A_,0)  ISSUE(A_,3)
    COMPU(B_,1)  ISSUE(B_,4)
    COMPU(C_,2)  ISSUE(C_,5)
    COMPU(A_,3)  ISSUE(A_,6)
    EPI_K(0) ZERO
    COMPU(B_,4)  ISSUE(B_,7)
    COMPU(C_,5)  ISSUE(C_,8)
    COMPU(A_,6)  ISSUE(A_,9)
    COMPU(B_,7)  ISSUE(B_,10)
    EPI_K(1) ZERO
    COMPU(C_,8)  ISSUE(C_,11)
    COMPU(A_,9)  ISSUE(A_,12)
    COMPU(B_,10) ISSUE(B_,13)
    COMPU(C_,11) ISSUE(C_,14)
    EPI_V(2) ZERO
    COMPU(A_,12) ISSUE(A_,15)
    COMPU(B_,13)
    COMPU(C_,14)
    COMPU(A_,15)
    EPI_V(3)

#undef ISSUE
#undef LDA
#undef MF
#undef COMPQ
#undef COMPU
#undef ZERO
#undef STK
#undef STV
#undef EPI_K
#undef EPI_V
}

// ---------------- fused LN(slots) + q projection -> bf16 [b][16][256] ----------------
__global__ __launch_bounds__(256) void k_lnq(const float* __restrict__ S,
                                             const float* __restrict__ g, const float* __restrict__ b,
                                             const float* __restrict__ Wq,
                                             unsigned short* __restrict__ qbf){
    __shared__ float sn[15*256];
    int tid = threadIdx.x, w = tid >> 6, lane = tid & 63;
    int bb = blockIdx.x;
    {
        float4 gv = ((const float4*)g)[lane], bv = ((const float4*)b)[lane];
        for (int r=w; r<15; r+=4){
            float4 v = *(const float4*)(S + ((size_t)bb*15 + r)*256 + lane*4);
            float s  = v.x+v.y+v.z+v.w;
            float ss = v.x*v.x+v.y*v.y+v.z*v.z+v.w*v.w;
            for (int mk=1;mk<64;mk<<=1){ s += __shfl_xor(s,mk); ss += __shfl_xor(ss,mk); }
            float mean = s*(1.f/256.f);
            float rstd = rsqrtf(ss*(1.f/256.f) - mean*mean + LN_EPS);
            float4 o;
            o.x = (v.x-mean)*rstd*gv.x + bv.x;
            o.y = (v.y-mean)*rstd*gv.y + bv.y;
            o.z = (v.z-mean)*rstd*gv.z + bv.z;
            o.w = (v.w-mean)*rstd*gv.w + bv.w;
            *(float4*)(sn + r*256 + lane*4) = o;
        }
    }
    __syncthreads();
    int c = tid;
    const float4* wr4 = (const float4*)(Wq + (size_t)c*256);
    float acc[15];
#pragma unroll
    for (int r=0;r<15;r++) acc[r] = 0.f;
    for (int e=0;e<64;e++){
        float4 wv = wr4[e];
#pragma unroll
        for (int r=0;r<15;r++){
            float4 sv = *(const float4*)(sn + r*256 + e*4);   // uniform -> LDS broadcast
            acc[r] += sv.x*wv.x + sv.y*wv.y + sv.z*wv.z + sv.w*wv.w;
        }
    }
#pragma unroll
    for (int r=0;r<15;r++) qbf[(size_t)bb*4096 + r*256 + c] = f2bf(acc[r]);
    qbf[(size_t)bb*4096 + 15*256 + c] = 0;
}

// ---------------- fused attention pass (MFMA) ----------------
// asum partials written per (b, n-block); no global atomics, no memset needed.
__global__ __launch_bounds__(256) void k_attn(const unsigned short* __restrict__ kbuf,
                                              const unsigned short* __restrict__ vT,
                                              const unsigned short* __restrict__ qbf,
                                              float* __restrict__ part, float* __restrict__ asump){
    __shared__ unsigned short qls[16*264];
    __shared__ unsigned short atn[4][16*72];
    __shared__ float asl[16];
    int tid = threadIdx.x;
    int w = tid >> 6, l = tid & 63;
    int b = blockIdx.y, n0 = blockIdx.x*256;
    if (tid < 16) asl[tid] = 0.f;
    {
        const short8* qg = (const short8*)(qbf + (size_t)b*4096);
        for (int i = tid; i < 512; i += 256){
            int row = i >> 5, cc = i & 31;
            *(short8*)&qls[row*264 + cc*8] = qg[i];
        }
    }
    __syncthreads();
    int lr = l & 15, lg = l >> 4;
    // phase 1: logits 16s x 64n per wave
    f32x4 acc[4];
#pragma unroll
    for (int t=0;t<4;t++) acc[t] = (f32x4){0.f,0.f,0.f,0.f};
    const unsigned short* kb = kbuf + ((size_t)(b*Nn) + n0 + w*64)*256;
#pragma unroll
    for (int ks=0; ks<8; ks++){
        short8 af = *(const short8*)&qls[lr*264 + ks*32 + lg*8];
#pragma unroll
        for (int t=0;t<4;t++){
            short8 bf = *(const short8*)(kb + ((size_t)(t*16+lr))*256 + ks*32 + lg*8);
            acc[t] = __builtin_amdgcn_mfma_f32_16x16x32_bf16(af, bf, acc[t], 0,0,0);
        }
    }
    // softmax over slots (per column n), write attn to LDS (bf16, A-layout ready)
    float asr[4] = {0.f,0.f,0.f,0.f};
#pragma unroll
    for (int t=0;t<4;t++){
        float v0=acc[t][0], v1=acc[t][1], v2=acc[t][2], v3=acc[t][3];
        if (lg==3) v3 = -1e30f;
        float m = fmaxf(fmaxf(v0,v1), fmaxf(v2,v3));
        m = fmaxf(m, __shfl_xor(m,16));
        m = fmaxf(m, __shfl_xor(m,32));
        float e0=__expf((v0-m)*0.0625f), e1=__expf((v1-m)*0.0625f),
              e2=__expf((v2-m)*0.0625f), e3=(lg==3)?0.f:__expf((v3-m)*0.0625f);
        float s = e0+e1+e2+e3;
        s += __shfl_xor(s,16); s += __shfl_xor(s,32);
        float inv = 1.f/s;
        e0*=inv; e1*=inv; e2*=inv; e3*=inv;
        unsigned short* a_ = &atn[w][0];
        int col = t*16 + lr;
        a_[(lg*4+0)*72+col] = f2bf(e0);
        a_[(lg*4+1)*72+col] = f2bf(e1);
        a_[(lg*4+2)*72+col] = f2bf(e2);
        a_[(lg*4+3)*72+col] = f2bf(e3);
        float p0=e0,p1=e1,p2=e2,p3=e3;
        for (int mk=1;mk<16;mk<<=1){
            p0+=__shfl_xor(p0,mk); p1+=__shfl_xor(p1,mk);
            p2+=__shfl_xor(p2,mk); p3+=__shfl_xor(p3,mk);
        }
        asr[0]+=p0; asr[1]+=p1; asr[2]+=p2; asr[3]+=p3;
    }
    if (lr == 0){
        atomicAdd(&asl[lg*4+0], asr[0]);
        atomicAdd(&asl[lg*4+1], asr[1]);
        atomicAdd(&asl[lg*4+2], asr[2]);
        atomicAdd(&asl[lg*4+3], asr[3]);
    }
    __syncthreads();   // atn[*] + asl complete
    // phase 2: wave w owns d-range [w*64, w*64+64); loops all 4 n-windows
    f32x4 ua[4];
#pragma unroll
    for (int dt=0;dt<4;dt++) ua[dt] = (f32x4){0.f,0.f,0.f,0.f};
    const unsigned short* vb = vT + (size_t)b*256*4096 + ((size_t)(w*64 + lr))*4096 + n0 + lg*8;
#pragma unroll
    for (int wn=0;wn<4;wn++)
#pragma unroll
        for (int kc=0;kc<2;kc++){
            short8 af = *(const short8*)&atn[wn][lr*72 + kc*32 + lg*8];
#pragma unroll
            for (int dt=0;dt<4;dt++){
                short8 bf = *(const short8*)(vb + (size_t)dt*16*4096 + wn*64 + kc*32);
                ua[dt] = __builtin_amdgcn_mfma_f32_16x16x32_bf16(af, bf, ua[dt], 0,0,0);
            }
        }
    float* pb = part + ((size_t)(b*16 + blockIdx.x))*4096;
#pragma unroll
    for (int dt=0;dt<4;dt++)
#pragma unroll
        for (int r=0;r<4;r++)
            pb[(lg*4+r)*256 + w*64 + dt*16 + lr] = ua[dt][r];
    if (tid < 15) asump[((size_t)(b*16 + blockIdx.x))*16 + tid] = asl[tid];
}

// ---------------- GRU gates (fused PART-reduce + asum-reduce) ----------------
__global__ __launch_bounds__(256) void k_gates(const float* __restrict__ part,
                                               const float* __restrict__ asump,
                                               const float* __restrict__ S,
                                               const float* __restrict__ wih, const float* __restrict__ whh,
                                               const float* __restrict__ bih, const float* __restrict__ bhh,
                                               float* __restrict__ gates){
    __shared__ float src[3840];
    __shared__ float asl[15];
    int b = blockIdx.y, x = blockIdx.x, tid = threadIdx.x;
    int c = x*256 + tid;
    bool isGI = (x < 3);
    if (isGI){
        const float4* p0 = (const float4*)(part + (size_t)b*16*4096);
        for (int i=tid; i<960; i+=256){
            float4 s = p0[i];
#pragma unroll
            for (int j=1;j<16;j++){
                float4 t = p0[j*1024 + i];
                s.x+=t.x; s.y+=t.y; s.z+=t.z; s.w+=t.w;
            }
            ((float4*)src)[i] = s;
        }
        if (tid < 15){
            float a = 0.f;
#pragma unroll
            for (int j=0;j<16;j++) a += asump[((size_t)b*16 + j)*16 + tid];
            asl[tid] = a;
        }
    } else {
        const float4* s0 = (const float4*)(S + (size_t)b*3840);
        for (int i=tid; i<960; i+=256) ((float4*)src)[i] = s0[i];
    }
    __syncthreads();
    const float* wrow = isGI ? (wih + (size_t)c*256) : (whh + (size_t)(c-768)*256);
    float bias = isGI ? bih[c] : bhh[c-768];
    const float4* w4 = (const float4*)wrow;
    float acc[15];
#pragma unroll
    for (int r=0;r<15;r++) acc[r] = 0.f;
    for (int e=0;e<64;e++){
        float4 wv = w4[e];
#pragma unroll
        for (int r=0;r<15;r++){
            float4 sv = *(const float4*)(src + r*256 + e*4);   // uniform -> LDS broadcast
            acc[r] += sv.x*wv.x + sv.y*wv.y + sv.z*wv.z + sv.w*wv.w;
        }
    }
#pragma unroll
    for (int r=0;r<15;r++){
        float v = acc[r];
        if (isGI) v *= 1.f/(asl[r] + EPSN);
        gates[((size_t)(b*15+r))*1536 + c] = v + bias;
    }
}

__global__ __launch_bounds__(256) void k_gru(const float* __restrict__ gates, const float* __restrict__ S,
                                             float* __restrict__ G){
    int row = blockIdx.x, d = threadIdx.x;
    const float* gr = gates + (size_t)row*1536;
    float ir=gr[d], iz=gr[256+d], inn=gr[512+d];
    float hr=gr[768+d], hz=gr[1024+d], hn=gr[1280+d];
    float r = sigm_(ir+hr), z = sigm_(iz+hz);
    float n = tanh_(inn + r*hn);
    float h = S[(size_t)row*Dd + d];
    G[(size_t)row*Dd + d] = (1.f-z)*n + z*h;
}

// ---------------- fused LN(G) + mlp1 ----------------
__global__ __launch_bounds__(256) void k_lnmlp1(const float* __restrict__ G,
                                                const float* __restrict__ g, const float* __restrict__ b,
                                                const float* __restrict__ w1, const float* __restrict__ b1,
                                                float* __restrict__ h1){
    __shared__ float sn[15*256];
    int tid = threadIdx.x, w = tid >> 6, lane = tid & 63;
    int bb = blockIdx.y;
    {
        float4 gv = ((const float4*)g)[lane], bv = ((const float4*)b)[lane];
        for (int r=w; r<15; r+=4){
            float4 v = *(const float4*)(G + ((size_t)bb*15 + r)*256 + lane*4);
            float s  = v.x+v.y+v.z+v.w;
            float ss = v.x*v.x+v.y*v.y+v.z*v.z+v.w*v.w;
            for (int mk=1;mk<64;mk<<=1){ s += __shfl_xor(s,mk); ss += __shfl_xor(ss,mk); }
            float mean = s*(1.f/256.f);
            float rstd = rsqrtf(ss*(1.f/256.f) - mean*mean + LN_EPS);
            float4 o;
            o.x = (v.x-mean)*rstd*gv.x + bv.x;
            o.y = (v.y-mean)*rstd*gv.y + bv.y;
            o.z = (v.z-mean)*rstd*gv.z + bv.z;
            o.w = (v.w-mean)*rstd*gv.w + bv.w;
            *(float4*)(sn + r*256 + lane*4) = o;
        }
    }
    __syncthreads();
    int c = blockIdx.x*256 + tid;
    const float4* w4 = (const float4*)(w1 + (size_t)c*256);
    float acc[15];
#pragma unroll
    for (int r=0;r<15;r++) acc[r] = 0.f;
    for (int e=0;e<64;e++){
        float4 wv = w4[e];
#pragma unroll
        for (int r=0;r<15;r++){
            float4 sv = *(const float4*)(sn + r*256 + e*4);   // uniform -> LDS broadcast
            acc[r] += sv.x*wv.x + sv.y*wv.y + sv.z*wv.z + sv.w*wv.w;
        }
    }
    float bias = b1[c];
#pragma unroll
    for (int r=0;r<15;r++)
        h1[((size_t)(bb*15+r))*Hh + c] = fmaxf(acc[r] + bias, 0.f);
}

__global__ __launch_bounds__(256) void k_mlp2(const float* __restrict__ G, const float* __restrict__ h1,
                                              const float* __restrict__ w2, const float* __restrict__ b2,
                                              float* __restrict__ S, float* __restrict__ dup){
    int b = blockIdx.x, c = threadIdx.x;
    const float4* w4 = (const float4*)(w2 + (size_t)c*512);
    const float4* h4 = (const float4*)(h1 + (size_t)b*Kk*Hh);
    float acc[15];
#pragma unroll
    for (int r=0;r<15;r++) acc[r] = 0.f;
    for (int e=0;e<128;e++){
        float4 wv = w4[e];
#pragma unroll
        for (int r=0;r<15;r++){
            float4 hv = h4[r*128+e];
            acc[r] += hv.x*wv.x + hv.y*wv.y + hv.z*wv.z + hv.w*wv.w;
        }
    }
    float bias = b2[c];
#pragma unroll
    for (int r=0;r<15;r++){
        size_t i = ((size_t)(b*Kk+r))*Dd + c;
        float val = G[i] + acc[r] + bias;
        S[i] = val;
        if (dup) dup[i] = val;
    }
}

// ---------------- final attention output (MFMA logits + softmax) ----------------
__global__ __launch_bounds__(256) void k_attn_out(const unsigned short* __restrict__ kbuf,
                                                  const unsigned short* __restrict__ qbf,
                                                  float* __restrict__ out){
    __shared__ unsigned short qls[16*264];
    int tid = threadIdx.x;
    int w = tid >> 6, l = tid & 63;
    int b = blockIdx.y, n0 = blockIdx.x*256;
    {
        const short8* qg = (const short8*)(qbf + (size_t)b*4096);
        for (int i = tid; i < 512; i += 256){
            int row = i >> 5, cc = i & 31;
            *(short8*)&qls[row*264 + cc*8] = qg[i];
        }
    }
    __syncthreads();
    int lr = l & 15, lg = l >> 4;
    f32x4 acc[4];
#pragma unroll
    for (int t=0;t<4;t++) acc[t] = (f32x4){0.f,0.f,0.f,0.f};
    const unsigned short* kb = kbuf + ((size_t)(b*Nn) + n0 + w*64)*256;
#pragma unroll
    for (int ks=0; ks<8; ks++){
        short8 af = *(const short8*)&qls[lr*264 + ks*32 + lg*8];
#pragma unroll
        for (int t=0;t<4;t++){
            short8 bf = *(const short8*)(kb + ((size_t)(t*16+lr))*256 + ks*32 + lg*8);
            acc[t] = __builtin_amdgcn_mfma_f32_16x16x32_bf16(af, bf, acc[t], 0,0,0);
        }
    }
#pragma unroll
    for (int t=0;t<4;t++){
        float v0=acc[t][0], v1=acc[t][1], v2=acc[t][2], v3=acc[t][3];
        if (lg==3) v3 = -1e30f;
        float m = fmaxf(fmaxf(v0,v1), fmaxf(v2,v3));
        m = fmaxf(m, __shfl_xor(m,16));
        m = fmaxf(m, __shfl_xor(m,32));
        float e0=__expf((v0-m)*0.0625f), e1=__expf((v1-m)*0.0625f),
              e2=__expf((v2-m)*0.0625f), e3=(lg==3)?0.f:__expf((v3-m)*0.0625f);
        float s = e0+e1+e2+e3;
        s += __shfl_xor(s,16); s += __shfl_xor(s,32);
        float inv = 1.f/s;
        int n = n0 + w*64 + t*16 + lr;
        float ee0=e0*inv, ee1=e1*inv, ee2=e2*inv, ee3=e3*inv;
        out[((size_t)(b*15 + lg*4+0))*4096 + n] = ee0;
        out[((size_t)(b*15 + lg*4+1))*4096 + n] = ee1;
        out[((size_t)(b*15 + lg*4+2))*4096 + n] = ee2;
        if (lg != 3) out[((size_t)(b*15 + lg*4+3))*4096 + n] = ee3;
    }
}

extern "C" void kernel_launch(void* const* d_in, const int* in_sizes, int n_in,
                              void* d_out, int out_size, void* d_ws, size_t ws_size,
                              hipStream_t stream) {
    const float* inputs = (const float*)d_in[0];
    const float* noise  = (const float*)d_in[1];
    const float* mu     = (const float*)d_in[2];
    const float* lsig   = (const float*)d_in[3];
    const float* Wq     = (const float*)d_in[4];
    const float* Wk     = (const float*)d_in[5];
    const float* Wv     = (const float*)d_in[6];
    const float* wih    = (const float*)d_in[7];
    const float* whh    = (const float*)d_in[8];
    const float* bih    = (const float*)d_in[9];
    const float* bhh    = (const float*)d_in[10];
    const float* w1     = (const float*)d_in[11];
    const float* b1     = (const float*)d_in[12];
    const float* w2     = (const float*)d_in[13];
    const float* b2     = (const float*)d_in[14];
    const float* lin_w  = (const float*)d_in[15];
    const float* lin_b  = (const float*)d_in[16];
    const float* lsl_w  = (const float*)d_in[17];
    const float* lsl_b  = (const float*)d_in[18];
    const float* lml_w  = (const float*)d_in[19];
    const float* lml_b  = (const float*)d_in[20];

    char* ws = (char*)d_ws;
    float*          PART = (float*)(ws + OFF_X);
    unsigned short* kbuf = (unsigned short*)(ws + OFF_K);
    unsigned short* vT   = (unsigned short*)(ws + OFF_VT);
    unsigned short* wc   = (unsigned short*)(ws + OFF_WC);
    unsigned short* QBF  = (unsigned short*)(ws + OFF_QBF);
    float* S     = (float*)(ws + OFF_S);
    float* G     = (float*)(ws + OFF_G);
    float* ASUMP = (float*)(ws + OFF_UPD);
    float* GT    = (float*)(ws + OFF_GT);
    float* H1    = (float*)(ws + OFF_H1);
    float* out   = (float*)d_out;

    k_prep_wc<<<512, 256, 0, stream>>>(Wk, Wv, wc);
    k_slots_init<<<960, 256, 0, stream>>>(mu, lsig, noise, S);
    k_proj<<<BN/128, 512, 0, stream>>>(inputs, lin_w, lin_b, wc, kbuf, vT);

    for (int it = 0; it < 3; it++){
        k_lnq<<<Bh, 256, 0, stream>>>(S, lsl_w, lsl_b, Wq, QBF);
        k_attn<<<dim3(16, Bh), 256, 0, stream>>>(kbuf, vT, QBF, PART, ASUMP);
        k_gates<<<dim3(6, Bh), 256, 0, stream>>>(PART, ASUMP, S, wih, whh, bih, bhh, GT);
        k_gru<<<960, 256, 0, stream>>>(GT, S, G);
        k_lnmlp1<<<dim3(2, Bh), 256, 0, stream>>>(G, lml_w, lml_b, w1, b1, H1);
        k_mlp2<<<Bh, 256, 0, stream>>>(G, H1, w2, b2, S, (it==2) ? out : (float*)nullptr);
    }

    k_lnq<<<Bh, 256, 0, stream>>>(S, lsl_w, lsl_b, Wq, QBF);
    k_attn_out<<<dim3(16, Bh), 256, 0, stream>>>(kbuf, QBF, out + 245760);
}